// Round 10
// baseline (227.974 us; speedup 1.0000x reference)
//
#include <hip/hip_runtime.h>
#include <hip/hip_bf16.h>
#include <cstdint>
#include <cstddef>

#define TAU 1e-4f
#define LN_EPS 1e-5f

typedef unsigned short ushort_t;
typedef unsigned int uint_t;
typedef __attribute__((ext_vector_type(8))) short short8;
typedef __attribute__((ext_vector_type(4))) float f32x4;

__device__ __forceinline__ ushort_t f2bf(float f) {
    union { float f; unsigned int u; } c; c.f = f;
    unsigned int r = (c.u + 0x7fffu + ((c.u >> 16) & 1u)) >> 16;
    return (ushort_t)r;
}
__device__ __forceinline__ float bf2f(uint_t u) {
    union { float f; uint_t u; } c; c.u = u << 16; return c.f;
}
__device__ __forceinline__ void glds16(const void* g, void* l) {
    __builtin_amdgcn_global_load_lds((const __attribute__((address_space(1))) unsigned int*)g,
                                     (__attribute__((address_space(3))) unsigned int*)l,
                                     16, 0, 0);
}

// ---------------------------------------------------------------------------
// kA': round-5 phases, but the Mcat tail is GONE (factorization moved the
// M-contraction to kC). New tail: store xn bf16 (xnb) + M matrices (Msg,
// parked per-b in the h slot: h+b*8192 bytes, block-disjoint with kC's h
// rewrite). Prep path: WzT[(rt*256+n)][q] = W_rt[q][n] (B^T for kZ, K=256).
// grid 1542.
// ---------------------------------------------------------------------------
__global__ __launch_bounds__(256) void kA(
    const float* __restrict__ xg, const float* __restrict__ maskg,
    const float* __restrict__ Wg, const float* __restrict__ bg,
    const float* __restrict__ ls, const float* __restrict__ g1,
    const float* __restrict__ b1, ushort_t* __restrict__ xnb,
    float* __restrict__ gbuf,
    const float* __restrict__ Wv, const float* __restrict__ We,
    const float* __restrict__ Wo, const float* __restrict__ bv,
    const float* __restrict__ be, const float* __restrict__ Wf1,
    const float* __restrict__ Wf2, ushort_t* __restrict__ WzT,
    ushort_t* __restrict__ Wf1T, ushort_t* __restrict__ Wf2T,
    float* __restrict__ cvpart, float* __restrict__ beWo,
    ushort_t* __restrict__ hM) {
    __shared__ __align__(16) float POOL[7968];
    const int tid = threadIdx.x;

    if (blockIdx.x >= 1024) {
        const int id = blockIdx.x - 1024;
        if (id < 384) {
            float (*rowS)[256] = (float(*)[256])POOL;
            const int q0 = (id & 63) * 4;
            const int w = id >> 6;
            const int half = w / 3, s = w - half * 3;
            const float* src = half ? We : Wv;
#pragma unroll
            for (int r = 0; r < 4; ++r)
                rowS[r][tid] = src[(size_t)(q0 + r) * 768 + s * 256 + tid];
            __syncthreads();
            const float* wo = Wo + (size_t)(half * 768 + s * 256) * 256 + tid;
            float a0 = 0.f, a1 = 0.f, a2 = 0.f, a3 = 0.f;
            for (int d = 0; d < 256; ++d) {
                float wv = wo[(size_t)d * 256];
                a0 += rowS[0][d] * wv; a1 += rowS[1][d] * wv;
                a2 += rowS[2][d] * wv; a3 += rowS[3][d] * wv;
            }
            const int rt = half * 3 + s;
            ushort4 pk;
            pk.x = f2bf(a0); pk.y = f2bf(a1); pk.z = f2bf(a2); pk.w = f2bf(a3);
            // WzT[(rt*256+n)][q0..q0+3] = W_rt[q0..q0+3][n]   (n = tid)
            *(ushort4*)&WzT[((size_t)(rt * 256 + tid)) * 256 + q0] = pk;
        } else if (id < 390) {
            const int w = id - 384;
            const int half = w / 3, s = w - half * 3;
            const float* vec = half ? be : bv;
            POOL[tid] = vec[s * 256 + tid];
            __syncthreads();
            const float* wo = Wo + (size_t)(half * 768 + s * 256) * 256 + tid;
            float acc = 0.f;
            for (int d = 0; d < 256; ++d) acc += POOL[d] * wo[(size_t)d * 256];
            if (half) beWo[s * 256 + tid] = acc;
            else cvpart[s * 256 + tid] = acc;
        } else {
            float (*tS)[65] = (float(*)[65])POOL;
            const float* src; ushort_t* dst;
            int sr0, sc0, ss, dr0, dc0, ds_;
            if (id < 454) {
                int t = id - 390; int ki = t & 3, ni = t >> 2;
                src = Wf1; ss = 1024; sr0 = ki * 64; sc0 = ni * 64;
                dst = Wf1T; ds_ = 256; dr0 = ni * 64; dc0 = ki * 64;
            } else {
                int t = id - 454; int ki = t >> 2, ni = t & 3;
                src = Wf2; ss = 256; sr0 = ki * 64; sc0 = ni * 64;
                dst = Wf2T; ds_ = 1024; dr0 = ni * 64; dc0 = ki * 64;
            }
            const int rl = tid >> 6, cl = tid & 63;
#pragma unroll
            for (int p = 0; p < 16; ++p) {
                int r = p * 4 + rl;
                tS[r][cl] = src[(size_t)(sr0 + r) * ss + sc0 + cl];
            }
            __syncthreads();
#pragma unroll
            for (int p = 0; p < 16; ++p) {
                int r = p * 4 + rl;
                dst[(size_t)(dr0 + r) * ds_ + dc0 + cl] = f2bf(tS[cl][r]);
            }
        }
        return;
    }

    // ---- per-b path ----
    const int b = blockIdx.x;
    float (*XS)[260] = (float(*)[260])POOL;
    float (*WgTh)[132] = (float(*)[132])(POOL + 4160);
    float (*Wh)[16][17] = (float(*)[16][17])(POOL + 6272);
    float* Ts = POOL + 7088;
    float (*Pl)[17] = (float(*)[17])(POOL + 7136);
    float (*dotm)[17] = (float(*)[17])(POOL + 7408);
    float (*DsqS)[17] = (float(*)[17])(POOL + 7680);
    float* mk = POOL + 7952;

    const float* xb = xg + (size_t)b * 4096;
#pragma unroll
    for (int i = 0; i < 4; ++i) {
        int idx = tid * 4 + i * 1024;
        int k = idx >> 8, c = idx & 255;
        float4 v = *(const float4*)&xb[idx];
        XS[k][c] = v.x; XS[k][c + 1] = v.y; XS[k][c + 2] = v.z; XS[k][c + 3] = v.w;
    }
    if (tid < 16) mk[tid] = maskg[b * 16 + tid];
    __syncthreads();

    // LN1
    {
        const int k = tid >> 4, c = tid & 15;
        float s = 0.f;
#pragma unroll
        for (int j = 0; j < 16; ++j) s += XS[k][c + 16 * j];
        for (int off = 8; off; off >>= 1) s += __shfl_down(s, off, 16);
        float mean = __shfl(s, 0, 16) * (1.f / 256.f);
        float vs = 0.f;
#pragma unroll
        for (int j = 0; j < 16; ++j) { float d = XS[k][c + 16 * j] - mean; vs += d * d; }
        for (int off = 8; off; off >>= 1) vs += __shfl_down(vs, off, 16);
        float rstd = rsqrtf(__shfl(vs, 0, 16) * (1.f / 256.f) + LN_EPS);
#pragma unroll
        for (int j = 0; j < 16; ++j) {
            int cc = c + 16 * j;
            XS[k][cc] = (XS[k][cc] - mean) * rstd * g1[cc] + b1[cc];
        }
    }
    __syncthreads();

    // store xn as bf16 (A-panel for kZ) — pair-packed, coalesced
    {
        ushort_t* xo = xnb + (size_t)b * 4096;
#pragma unroll
        for (int i = 0; i < 8; ++i) {
            int flat = i * 512 + tid * 2;
            int k = flat >> 8, c = flat & 255;
            uint_t pk = (uint_t)f2bf(XS[k][c]) | ((uint_t)f2bf(XS[k][c + 1]) << 16);
            *(uint_t*)&xo[flat] = pk;
        }
    }

    // P[k][c] in two q-half passes
    {
        const int k = tid >> 4, c = tid & 15;
        const int ql = tid >> 1, hf = tid & 1;
        float acc = bg[c];
        {
            const float4* wp = (const float4*)(Wg + ql * 16 + hf * 8);
            float4 w0 = wp[0], w1 = wp[1];
            WgTh[hf * 8 + 0][ql] = w0.x; WgTh[hf * 8 + 1][ql] = w0.y;
            WgTh[hf * 8 + 2][ql] = w0.z; WgTh[hf * 8 + 3][ql] = w0.w;
            WgTh[hf * 8 + 4][ql] = w1.x; WgTh[hf * 8 + 5][ql] = w1.y;
            WgTh[hf * 8 + 6][ql] = w1.z; WgTh[hf * 8 + 7][ql] = w1.w;
        }
        __syncthreads();
        const float4* wp2 = (const float4*)(Wg + (128 + ql) * 16 + hf * 8);
        float4 w20 = wp2[0], w21 = wp2[1];
#pragma unroll
        for (int q4 = 0; q4 < 32; ++q4) {
            float4 wv = *(const float4*)&WgTh[c][q4 * 4];
            float4 xv = *(const float4*)&XS[k][q4 * 4];
            acc += wv.x * xv.x + wv.y * xv.y + wv.z * xv.z + wv.w * xv.w;
        }
        __syncthreads();
        WgTh[hf * 8 + 0][ql] = w20.x; WgTh[hf * 8 + 1][ql] = w20.y;
        WgTh[hf * 8 + 2][ql] = w20.z; WgTh[hf * 8 + 3][ql] = w20.w;
        WgTh[hf * 8 + 4][ql] = w21.x; WgTh[hf * 8 + 5][ql] = w21.y;
        WgTh[hf * 8 + 6][ql] = w21.z; WgTh[hf * 8 + 7][ql] = w21.w;
        __syncthreads();
#pragma unroll
        for (int q4 = 0; q4 < 32; ++q4) {
            float4 wv = *(const float4*)&WgTh[c][q4 * 4];
            float4 xv = *(const float4*)&XS[k][128 + q4 * 4];
            acc += wv.x * xv.x + wv.y * xv.y + wv.z * xv.z + wv.w * xv.w;
        }
        Pl[k][c] = acc;
    }
    __syncthreads();
    const int k = tid >> 4, m = tid & 15;
    {
        float d = 0.f;
#pragma unroll
        for (int c = 0; c < 16; ++c) d += Pl[k][c] * Pl[m][c];
        dotm[k][m] = d;
    }
    __syncthreads();
    {
        float v = dotm[k][k] + dotm[m][m] - 2.f * dotm[k][m];
        DsqS[k][m] = fmaxf(v, 0.f) * mk[k] * mk[m];
    }
    {
        float d = DsqS[k][m];
        float mm = mk[k] * mk[m];
#pragma unroll
        for (int s = 0; s < 3; ++s) {
            float i2 = 1.f / (2.f * expf(2.f * ls[s]) + 1e-8f);
            Wh[s][k][m] = (k == m) ? 0.f : expf(-d * i2) * mm;
        }
    }
    __syncthreads();
    if (tid < 48) {
        int s = tid >> 4, j = tid & 15;
        float t = 0.f;
        for (int i = 0; i < j; ++i) {
            float d = 0.f;
            for (int jj = j + 1; jj < 16; ++jj) d += Wh[s][j][jj] * Wh[s][i][jj];
            t += Wh[s][i][j] * d;
        }
        Ts[s * 16 + j] = t;
    }
    __syncthreads();
    float gd = 0.f;
#pragma unroll
    for (int o = 0; o < 16; ++o) {
        if (o == m) continue;
        int u = o < m ? o : m, v = o < m ? m : o;
        float gu = (u == k) ? (float)(2 * k - 15) : ((u > k) ? 1.f : -1.f);
        float gv = (v == k) ? (float)(2 * k - 15) : ((v > k) ? 1.f : -1.f);
        gd += -gu * mk[u] + gv * mk[v];
        if (u == k || v == k) gd += TAU;
    }
    // M matrices straight to global (Msg parked in h slot, per-b 8192B)
    {
        float* MsgB = (float*)(hM + (size_t)b * 4096);
#pragma unroll
        for (int s = 0; s < 3; ++s) {
            float rs = 0.f;
#pragma unroll
            for (int o = 0; o < 16; ++o) rs += Wh[s][k][o];
            float l0 = (k == m) ? (rs + TAU) : -Wh[s][k][m];
            float G = gd + ((k == m) ? 4.f * Ts[s * 16 + k] : 0.f);
            MsgB[s * 256 + tid] = l0;
            MsgB[768 + s * 256 + tid] = G;
            float gg = G;
            for (int off = 8; off; off >>= 1) gg += __shfl_down(gg, off, 16);
            if (m == 0) gbuf[b * 48 + k * 3 + s] = 0.5f * gg;
        }
    }
}

// ---------------------------------------------------------------------------
// gemm64_db: 64x128 tile, BK=32, 2-phase double-buffer (round-3 proven).
// ---------------------------------------------------------------------------
__device__ __forceinline__ void gemm64_db(
    const ushort_t* __restrict__ A, const ushort_t* __restrict__ Bt,
    int Kdim, int m0, int n0, f32x4 acc[2][4],
    ushort_t (*As0)[32], ushort_t (*As1)[32],
    ushort_t (*Bs0)[32], ushort_t (*Bs1)[32]) {
    const int tid = threadIdx.x;
    const int wave = tid >> 6, lane = tid & 63;
    const int lq = lane >> 4, lr = lane & 15;
    const int wm = wave >> 1, wn = wave & 1;
    const int r = tid >> 2, ca = (tid & 3) << 3;
    const ushort_t* Ag  = A  + (size_t)(m0 + r) * Kdim + ca;
    const ushort_t* Bg0 = Bt + (size_t)(n0 + r) * Kdim + ca;
    const ushort_t* Bg1 = Bt + (size_t)(n0 + 64 + r) * Kdim + ca;
    char* aD0  = (char*)As0 + wave * 1024;
    char* aD1  = (char*)As1 + wave * 1024;
    char* b0D0 = (char*)Bs0 + wave * 1024;
    char* b0D1 = (char*)Bs0 + 4096 + wave * 1024;
    char* b1D0 = (char*)Bs1 + wave * 1024;
    char* b1D1 = (char*)Bs1 + 4096 + wave * 1024;

    glds16(Ag, aD0); glds16(Bg0, b0D0); glds16(Bg1, b0D1);

    for (int kt = 0; kt < Kdim; kt += 64) {
        {
            const int kn = kt + 32;
            if (kn < Kdim) {
                glds16(Ag + kn, aD1); glds16(Bg0 + kn, b1D0); glds16(Bg1 + kn, b1D1);
                asm volatile("s_waitcnt vmcnt(3)" ::: "memory");
            } else {
                asm volatile("s_waitcnt vmcnt(0)" ::: "memory");
            }
            __builtin_amdgcn_s_barrier();
            short8 af[2], bfr[4];
#pragma unroll
            for (int i = 0; i < 2; ++i) af[i] = *(const short8*)&As0[wm * 32 + i * 16 + lr][lq * 8];
#pragma unroll
            for (int j = 0; j < 4; ++j) bfr[j] = *(const short8*)&Bs0[wn * 64 + j * 16 + lr][lq * 8];
#pragma unroll
            for (int i = 0; i < 2; ++i)
#pragma unroll
                for (int j = 0; j < 4; ++j)
                    acc[i][j] = __builtin_amdgcn_mfma_f32_16x16x32_bf16(af[i], bfr[j], acc[i][j], 0, 0, 0);
            asm volatile("s_waitcnt lgkmcnt(0)" ::: "memory");
            __builtin_amdgcn_s_barrier();
        }
        {
            const int kn = kt + 64;
            if (kn < Kdim) {
                glds16(Ag + kn, aD0); glds16(Bg0 + kn, b0D0); glds16(Bg1 + kn, b0D1);
                asm volatile("s_waitcnt vmcnt(3)" ::: "memory");
            } else {
                asm volatile("s_waitcnt vmcnt(0)" ::: "memory");
            }
            __builtin_amdgcn_s_barrier();
            short8 af[2], bfr[4];
#pragma unroll
            for (int i = 0; i < 2; ++i) af[i] = *(const short8*)&As1[wm * 32 + i * 16 + lr][lq * 8];
#pragma unroll
            for (int j = 0; j < 4; ++j) bfr[j] = *(const short8*)&Bs1[wn * 64 + j * 16 + lr][lq * 8];
#pragma unroll
            for (int i = 0; i < 2; ++i)
#pragma unroll
                for (int j = 0; j < 4; ++j)
                    acc[i][j] = __builtin_amdgcn_mfma_f32_16x16x32_bf16(af[i], bfr[j], acc[i][j], 0, 0, 0);
            asm volatile("s_waitcnt lgkmcnt(0)" ::: "memory");
            __builtin_amdgcn_s_barrier();
        }
    }
}

// kZ: Zcat = xnb @ Wcat.  M=16384, N=1536, K=256. 64x128 tiles,
// grid (256,12) = 3072 blocks. Same FLOPs as old kZY, far better shape.
__global__ __launch_bounds__(256) void kZ_gemm(const ushort_t* __restrict__ xnb,
                                               const ushort_t* __restrict__ WzT,
                                               ushort_t* __restrict__ Zcat) {
    __shared__ ushort_t As0[64][32], As1[64][32];
    __shared__ ushort_t Bs0[128][32], Bs1[128][32];
    const int tid = threadIdx.x;
    const int m0 = blockIdx.x * 64, n0 = blockIdx.y * 128;
    f32x4 acc[2][4] = {};
    gemm64_db(xnb, WzT, 256, m0, n0, acc, As0, As1, Bs0, Bs1);
    const int wave = tid >> 6, lane = tid & 63, lq = lane >> 4, lr = lane & 15;
    const int wm = wave >> 1, wn = wave & 1;
#pragma unroll
    for (int i = 0; i < 2; ++i)
#pragma unroll
        for (int j = 0; j < 4; ++j) {
            int n = n0 + wn * 64 + j * 16 + lr;
#pragma unroll
            for (int v = 0; v < 4; ++v) {
                int rg = m0 + wm * 32 + i * 16 + lq * 4 + v;
                Zcat[(size_t)rg * 1536 + n] = f2bf(acc[i][j][v]);
            }
        }
}

// ---------------------------------------------------------------------------
// kC: per-b combine + residual + fused LN2. grid 1024 (block = b), 256 thr.
//   xp[b,k,n] = sum_rt sum_l M_rt[k][l] * Z[b,l,rt,n] + x + cv + g.beWo
// then LN2 on the 16 rows (in LDS) -> h. h overwrites Msg[b] (reads done).
// Thread layout: half = tid>>7 handles rt 0-2 / 3-5, cols q2,q2+1.
// ---------------------------------------------------------------------------
__global__ __launch_bounds__(256) void kC(
    const ushort_t* __restrict__ Zcat, const float* __restrict__ xg,
    const float* __restrict__ bo, const float* __restrict__ cvpart,
    const float* __restrict__ beWo, const float* __restrict__ gbuf,
    const float* __restrict__ g2, const float* __restrict__ b2,
    float* __restrict__ xp, ushort_t* __restrict__ hM) {
    __shared__ float MsS[1536];
    __shared__ float xpS[16][258];
    __shared__ float gS[48];
    const int tid = threadIdx.x;
    const int b = blockIdx.x;
    const float* MsgB = (const float*)(hM + (size_t)b * 4096);
#pragma unroll
    for (int i = 0; i < 6; ++i) MsS[tid + i * 256] = MsgB[tid + i * 256];
    if (tid < 48) gS[tid] = gbuf[b * 48 + tid];
    __syncthreads();

    const int half = tid >> 7, q2 = (tid & 127) * 2;
    float acc0[16], acc1[16];
#pragma unroll
    for (int k = 0; k < 16; ++k) { acc0[k] = 0.f; acc1[k] = 0.f; }
    const ushort_t* zb = Zcat + (size_t)b * 16 * 1536;
#pragma unroll
    for (int rtt = 0; rtt < 3; ++rtt) {
        const int rt = half * 3 + rtt;
        float zr0[16], zr1[16];
#pragma unroll
        for (int l = 0; l < 16; ++l) {
            uint_t zz = *(const uint_t*)&zb[(size_t)l * 1536 + rt * 256 + q2];
            zr0[l] = bf2f(zz & 0xffffu);
            zr1[l] = bf2f(zz >> 16);
        }
        const float* Mrt = MsS + rt * 256;
#pragma unroll
        for (int k = 0; k < 16; ++k) {
            const float4* mp = (const float4*)&Mrt[k * 16];
            float4 m0 = mp[0], m1 = mp[1], m2 = mp[2], m3 = mp[3];
            acc0[k] += m0.x * zr0[0] + m0.y * zr0[1] + m0.z * zr0[2] + m0.w * zr0[3]
                     + m1.x * zr0[4] + m1.y * zr0[5] + m1.z * zr0[6] + m1.w * zr0[7]
                     + m2.x * zr0[8] + m2.y * zr0[9] + m2.z * zr0[10] + m2.w * zr0[11]
                     + m3.x * zr0[12] + m3.y * zr0[13] + m3.z * zr0[14] + m3.w * zr0[15];
            acc1[k] += m0.x * zr1[0] + m0.y * zr1[1] + m0.z * zr1[2] + m0.w * zr1[3]
                     + m1.x * zr1[4] + m1.y * zr1[5] + m1.z * zr1[6] + m1.w * zr1[7]
                     + m2.x * zr1[8] + m2.y * zr1[9] + m2.z * zr1[10] + m2.w * zr1[11]
                     + m3.x * zr1[12] + m3.y * zr1[13] + m3.z * zr1[14] + m3.w * zr1[15];
        }
    }
    if (half == 0) {
        float cv0 = bo[q2] + TAU * (cvpart[q2] + cvpart[256 + q2] + cvpart[512 + q2]);
        float cv1 = bo[q2 + 1] + TAU * (cvpart[q2 + 1] + cvpart[256 + q2 + 1] + cvpart[512 + q2 + 1]);
        float bw00 = beWo[q2], bw01 = beWo[q2 + 1];
        float bw10 = beWo[256 + q2], bw11 = beWo[256 + q2 + 1];
        float bw20 = beWo[512 + q2], bw21 = beWo[512 + q2 + 1];
#pragma unroll
        for (int k = 0; k < 16; ++k) {
            float2 xv = *(const float2*)&xg[((size_t)b * 16 + k) * 256 + q2];
            float ga0 = gS[k * 3], ga1 = gS[k * 3 + 1], ga2 = gS[k * 3 + 2];
            xpS[k][q2]     = acc0[k] + xv.x + cv0 + ga0 * bw00 + ga1 * bw10 + ga2 * bw20;
            xpS[k][q2 + 1] = acc1[k] + xv.y + cv1 + ga0 * bw01 + ga1 * bw11 + ga2 * bw21;
        }
    }
    __syncthreads();
    if (half == 1) {
#pragma unroll
        for (int k = 0; k < 16; ++k) { xpS[k][q2] += acc0[k]; xpS[k][q2 + 1] += acc1[k]; }
    }
    __syncthreads();
    // xp store
#pragma unroll
    for (int k = 0; k < 16; ++k)
        xp[((size_t)b * 16 + k) * 256 + tid] = xpS[k][tid];
    // fused LN2 -> h (wave wv handles rows 4wv..4wv+3)
    const int lane = tid & 63, wv = tid >> 6;
#pragma unroll
    for (int rr = 0; rr < 4; ++rr) {
        const int row = wv * 4 + rr;
        float v0 = xpS[row][lane], v1 = xpS[row][lane + 64];
        float v2 = xpS[row][lane + 128], v3 = xpS[row][lane + 192];
        float s = v0 + v1 + v2 + v3;
        for (int mo = 32; mo; mo >>= 1) s += __shfl_xor(s, mo, 64);
        float mean = s * (1.f / 256.f);
        float d0 = v0 - mean, d1 = v1 - mean, d2 = v2 - mean, d3 = v3 - mean;
        float qq = d0 * d0 + d1 * d1 + d2 * d2 + d3 * d3;
        for (int mo = 32; mo; mo >>= 1) qq += __shfl_xor(qq, mo, 64);
        float rstd = rsqrtf(qq * (1.f / 256.f) + LN_EPS);
        ushort_t* hr = hM + ((size_t)b * 16 + row) * 256;
        hr[lane] = f2bf(d0 * rstd * g2[lane] + b2[lane]);
        hr[lane + 64] = f2bf(d1 * rstd * g2[lane + 64] + b2[lane + 64]);
        hr[lane + 128] = f2bf(d2 * rstd * g2[lane + 128] + b2[lane + 128]);
        hr[lane + 192] = f2bf(d3 * rstd * g2[lane + 192] + b2[lane + 192]);
    }
}

// K3: F1g = gelu(h @ Wf1 + bf1), 64x128 tiles, grid (256,8) = 2048 blocks
__global__ __launch_bounds__(256) void k3_gemm(const ushort_t* __restrict__ h,
                                               const ushort_t* __restrict__ Wf1T,
                                               const float* __restrict__ bf1,
                                               ushort_t* __restrict__ F1g) {
    __shared__ ushort_t As0[64][32], As1[64][32];
    __shared__ ushort_t Bs0[128][32], Bs1[128][32];
    const int tid = threadIdx.x;
    const int m0 = blockIdx.x * 64, n0 = blockIdx.y * 128;
    f32x4 acc[2][4] = {};
    gemm64_db(h, Wf1T, 256, m0, n0, acc, As0, As1, Bs0, Bs1);
    const int wave = tid >> 6, lane = tid & 63, lq = lane >> 4, lr = lane & 15;
    const int wm = wave >> 1, wn = wave & 1;
#pragma unroll
    for (int i = 0; i < 2; ++i)
#pragma unroll
        for (int j = 0; j < 4; ++j) {
            int n = n0 + wn * 64 + j * 16 + lr;
            float bn = bf1[n];
#pragma unroll
            for (int v = 0; v < 4; ++v) {
                int rg = m0 + wm * 32 + i * 16 + lq * 4 + v;
                float u = acc[i][j][v] + bn;
                float gl = 0.5f * u * (1.f + erff(u * 0.70710678118f));
                F1g[(size_t)rg * 1024 + n] = f2bf(gl);
            }
        }
}

// K4: out = xp + F1g @ Wf2 + bf2, 64x128 tiles, grid (256,2)
__global__ __launch_bounds__(256) void k4_gemm(const ushort_t* __restrict__ F1g,
                                               const ushort_t* __restrict__ Wf2T,
                                               const float* __restrict__ bf2,
                                               const float* __restrict__ xp,
                                               float* __restrict__ out) {
    __shared__ ushort_t As0[64][32], As1[64][32];
    __shared__ ushort_t Bs0[128][32], Bs1[128][32];
    const int tid = threadIdx.x;
    const int m0 = blockIdx.x * 64, n0 = blockIdx.y * 128;
    f32x4 acc[2][4] = {};
    gemm64_db(F1g, Wf2T, 1024, m0, n0, acc, As0, As1, Bs0, Bs1);
    const int wave = tid >> 6, lane = tid & 63, lq = lane >> 4, lr = lane & 15;
    const int wm = wave >> 1, wn = wave & 1;
#pragma unroll
    for (int i = 0; i < 2; ++i)
#pragma unroll
        for (int j = 0; j < 4; ++j) {
            int n = n0 + wn * 64 + j * 16 + lr;
            float bn = bf2[n];
#pragma unroll
            for (int v = 0; v < 4; ++v) {
                size_t idx = (size_t)(m0 + wm * 32 + i * 16 + lq * 4 + v) * 256 + n;
                out[idx] = xp[idx] + acc[i][j][v] + bn;
            }
        }
}

extern "C" void kernel_launch(void* const* d_in, const int* in_sizes, int n_in,
                              void* d_out, int out_size, void* d_ws, size_t ws_size,
                              hipStream_t stream) {
    const float* x = (const float*)d_in[0];
    const float* mask = (const float*)d_in[1];
    const float* Wg = (const float*)d_in[2];
    const float* bg = (const float*)d_in[3];
    const float* ls = (const float*)d_in[4];
    const float* Wv = (const float*)d_in[5];
    const float* bv = (const float*)d_in[6];
    const float* We = (const float*)d_in[7];
    const float* be = (const float*)d_in[8];
    const float* Wo = (const float*)d_in[9];
    const float* bo = (const float*)d_in[10];
    const float* g1 = (const float*)d_in[11];
    const float* b1 = (const float*)d_in[12];
    const float* g2 = (const float*)d_in[13];
    const float* b2 = (const float*)d_in[14];
    const float* Wf1 = (const float*)d_in[15];
    const float* bf1 = (const float*)d_in[16];
    const float* Wf2 = (const float*)d_in[17];
    const float* bf2 = (const float*)d_in[18];
    float* out = (float*)d_out;

    char* ws = (char*)d_ws;
    // slot 0 [0, 50,331,648): Zcat (kZ->kC), then F1g (k3->k4) aliases [0,33.5MB)
    ushort_t* Zcat = (ushort_t*)(ws);
    ushort_t* F1g = (ushort_t*)(ws);
    ushort_t* WzT = (ushort_t*)(ws + 50331648);         //    786,432
    ushort_t* Wf1T = (ushort_t*)(ws + 51118080);        //    524,288
    ushort_t* Wf2T = (ushort_t*)(ws + 51642368);        //    524,288
    float* cvpart = (float*)(ws + 52166656);            //      3,072
    float* beWo = (float*)(ws + 52169728);              //      3,072
    float* gbuf = (float*)(ws + 52172800);              //    196,608
    // xp slot [52,369,408, 69,146,624): xnb (kA->kZ) aliases first 8.4MB,
    // then xp (kC->k4) — lifetimes disjoint (kZ completes before kC writes).
    ushort_t* xnb = (ushort_t*)(ws + 52369408);
    float* xp = (float*)(ws + 52369408);
    // h slot [69,146,624, 77,535,232): per-b 8192B: Msg (kA->kC reads) then
    // h rows of the SAME b written by the SAME kC block — block-disjoint.
    ushort_t* hM = (ushort_t*)(ws + 69146624);

    kA<<<dim3(1542), dim3(256), 0, stream>>>(x, mask, Wg, bg, ls, g1, b1,
                                             xnb, gbuf,
                                             Wv, We, Wo, bv, be, Wf1, Wf2,
                                             WzT, Wf1T, Wf2T, cvpart, beWo, hM);
    kZ_gemm<<<dim3(256, 12), dim3(256), 0, stream>>>(xnb, WzT, Zcat);
    kC<<<dim3(1024), dim3(256), 0, stream>>>(Zcat, x, bo, cvpart, beWo, gbuf,
                                             g2, b2, xp, hM);
    k3_gemm<<<dim3(256, 8), dim3(256), 0, stream>>>(hM, Wf1T, bf1, F1g);
    k4_gemm<<<dim3(256, 2), dim3(256), 0, stream>>>(F1g, Wf2T, bf2, xp, out);
}

// Round 11
// 212.079 us; speedup vs baseline: 1.0749x; 1.0749x over previous
//
#include <hip/hip_runtime.h>
#include <hip/hip_bf16.h>
#include <cstdint>
#include <cstddef>

#define TAU 1e-4f
#define LN_EPS 1e-5f

typedef unsigned short ushort_t;
typedef unsigned int uint_t;
typedef __attribute__((ext_vector_type(8))) short short8;
typedef __attribute__((ext_vector_type(4))) float f32x4;

__device__ __forceinline__ ushort_t f2bf(float f) {
    union { float f; unsigned int u; } c; c.f = f;
    unsigned int r = (c.u + 0x7fffu + ((c.u >> 16) & 1u)) >> 16;
    return (ushort_t)r;
}
__device__ __forceinline__ void glds16(const void* g, void* l) {
    __builtin_amdgcn_global_load_lds((const __attribute__((address_space(1))) unsigned int*)g,
                                     (__attribute__((address_space(3))) unsigned int*)l,
                                     16, 0, 0);
}

// ---------------------------------------------------------------------------
// kA: round-5 version (measured == round-0 perf, 32KB LDS). merged
// weight-prep + per-b LN1/graph/Mcat kernel. grid 1542.
// ---------------------------------------------------------------------------
__global__ __launch_bounds__(256) void kA(
    const float* __restrict__ xg, const float* __restrict__ maskg,
    const float* __restrict__ Wg, const float* __restrict__ bg,
    const float* __restrict__ ls, const float* __restrict__ g1,
    const float* __restrict__ b1, ushort_t* __restrict__ Mcat,
    float* __restrict__ gbuf,
    const float* __restrict__ Wv, const float* __restrict__ We,
    const float* __restrict__ Wo, const float* __restrict__ bv,
    const float* __restrict__ be, const float* __restrict__ Wf1,
    const float* __restrict__ Wf2, ushort_t* __restrict__ WcatT,
    ushort_t* __restrict__ Wf1T, ushort_t* __restrict__ Wf2T,
    float* __restrict__ cvpart, float* __restrict__ beWo) {
    __shared__ __align__(16) float POOL[7968];
    const int tid = threadIdx.x;

    if (blockIdx.x >= 1024) {
        const int id = blockIdx.x - 1024;
        if (id < 384) {
            float (*rowS)[256] = (float(*)[256])POOL;
            const int q0 = (id & 63) * 4;
            const int w = id >> 6;
            const int half = w / 3, s = w - half * 3;
            const float* src = half ? We : Wv;
#pragma unroll
            for (int r = 0; r < 4; ++r)
                rowS[r][tid] = src[(size_t)(q0 + r) * 768 + s * 256 + tid];
            __syncthreads();
            const float* wo = Wo + (size_t)(half * 768 + s * 256) * 256 + tid;
            float a0 = 0.f, a1 = 0.f, a2 = 0.f, a3 = 0.f;
            for (int d = 0; d < 256; ++d) {
                float wv = wo[(size_t)d * 256];
                a0 += rowS[0][d] * wv; a1 += rowS[1][d] * wv;
                a2 += rowS[2][d] * wv; a3 += rowS[3][d] * wv;
            }
            const int rt = half * 3 + s;
            ushort4 pk;
            pk.x = f2bf(a0); pk.y = f2bf(a1); pk.z = f2bf(a2); pk.w = f2bf(a3);
            *(ushort4*)&WcatT[(size_t)tid * 1536 + rt * 256 + q0] = pk;
        } else if (id < 390) {
            const int w = id - 384;
            const int half = w / 3, s = w - half * 3;
            const float* vec = half ? be : bv;
            POOL[tid] = vec[s * 256 + tid];
            __syncthreads();
            const float* wo = Wo + (size_t)(half * 768 + s * 256) * 256 + tid;
            float acc = 0.f;
            for (int d = 0; d < 256; ++d) acc += POOL[d] * wo[(size_t)d * 256];
            if (half) beWo[s * 256 + tid] = acc;
            else cvpart[s * 256 + tid] = acc;
        } else {
            float (*tS)[65] = (float(*)[65])POOL;
            const float* src; ushort_t* dst;
            int sr0, sc0, ss, dr0, dc0, ds_;
            if (id < 454) {
                int t = id - 390; int ki = t & 3, ni = t >> 2;
                src = Wf1; ss = 1024; sr0 = ki * 64; sc0 = ni * 64;
                dst = Wf1T; ds_ = 256; dr0 = ni * 64; dc0 = ki * 64;
            } else {
                int t = id - 454; int ki = t >> 2, ni = t & 3;
                src = Wf2; ss = 256; sr0 = ki * 64; sc0 = ni * 64;
                dst = Wf2T; ds_ = 1024; dr0 = ni * 64; dc0 = ki * 64;
            }
            const int rl = tid >> 6, cl = tid & 63;
#pragma unroll
            for (int p = 0; p < 16; ++p) {
                int r = p * 4 + rl;
                tS[r][cl] = src[(size_t)(sr0 + r) * ss + sc0 + cl];
            }
            __syncthreads();
#pragma unroll
            for (int p = 0; p < 16; ++p) {
                int r = p * 4 + rl;
                dst[(size_t)(dr0 + r) * ds_ + dc0 + cl] = f2bf(tS[cl][r]);
            }
        }
        return;
    }

    // ---- per-b path ----
    const int b = blockIdx.x;
    float (*XS)[260] = (float(*)[260])POOL;
    float (*WgTh)[132] = (float(*)[132])(POOL + 4160);
    float* Ms = POOL + 4160;
    float (*Wh)[16][17] = (float(*)[16][17])(POOL + 6272);
    float* Ts = POOL + 7088;
    float (*Pl)[17] = (float(*)[17])(POOL + 7136);
    float (*dotm)[17] = (float(*)[17])(POOL + 7408);
    float (*DsqS)[17] = (float(*)[17])(POOL + 7680);
    float* mk = POOL + 7952;

    const float* xb = xg + (size_t)b * 4096;
#pragma unroll
    for (int i = 0; i < 4; ++i) {
        int idx = tid * 4 + i * 1024;
        int k = idx >> 8, c = idx & 255;
        float4 v = *(const float4*)&xb[idx];
        XS[k][c] = v.x; XS[k][c + 1] = v.y; XS[k][c + 2] = v.z; XS[k][c + 3] = v.w;
    }
    if (tid < 16) mk[tid] = maskg[b * 16 + tid];
    __syncthreads();

    // LN1
    {
        const int k = tid >> 4, c = tid & 15;
        float s = 0.f;
#pragma unroll
        for (int j = 0; j < 16; ++j) s += XS[k][c + 16 * j];
        for (int off = 8; off; off >>= 1) s += __shfl_down(s, off, 16);
        float mean = __shfl(s, 0, 16) * (1.f / 256.f);
        float vs = 0.f;
#pragma unroll
        for (int j = 0; j < 16; ++j) { float d = XS[k][c + 16 * j] - mean; vs += d * d; }
        for (int off = 8; off; off >>= 1) vs += __shfl_down(vs, off, 16);
        float rstd = rsqrtf(__shfl(vs, 0, 16) * (1.f / 256.f) + LN_EPS);
#pragma unroll
        for (int j = 0; j < 16; ++j) {
            int cc = c + 16 * j;
            XS[k][cc] = (XS[k][cc] - mean) * rstd * g1[cc] + b1[cc];
        }
    }
    __syncthreads();

    // P[k][c] in two q-half passes
    {
        const int k = tid >> 4, c = tid & 15;
        const int ql = tid >> 1, hf = tid & 1;
        float acc = bg[c];
        {
            const float4* wp = (const float4*)(Wg + ql * 16 + hf * 8);
            float4 w0 = wp[0], w1 = wp[1];
            WgTh[hf * 8 + 0][ql] = w0.x; WgTh[hf * 8 + 1][ql] = w0.y;
            WgTh[hf * 8 + 2][ql] = w0.z; WgTh[hf * 8 + 3][ql] = w0.w;
            WgTh[hf * 8 + 4][ql] = w1.x; WgTh[hf * 8 + 5][ql] = w1.y;
            WgTh[hf * 8 + 6][ql] = w1.z; WgTh[hf * 8 + 7][ql] = w1.w;
        }
        __syncthreads();
        const float4* wp2 = (const float4*)(Wg + (128 + ql) * 16 + hf * 8);
        float4 w20 = wp2[0], w21 = wp2[1];
#pragma unroll
        for (int q4 = 0; q4 < 32; ++q4) {
            float4 wv = *(const float4*)&WgTh[c][q4 * 4];
            float4 xv = *(const float4*)&XS[k][q4 * 4];
            acc += wv.x * xv.x + wv.y * xv.y + wv.z * xv.z + wv.w * xv.w;
        }
        __syncthreads();
        WgTh[hf * 8 + 0][ql] = w20.x; WgTh[hf * 8 + 1][ql] = w20.y;
        WgTh[hf * 8 + 2][ql] = w20.z; WgTh[hf * 8 + 3][ql] = w20.w;
        WgTh[hf * 8 + 4][ql] = w21.x; WgTh[hf * 8 + 5][ql] = w21.y;
        WgTh[hf * 8 + 6][ql] = w21.z; WgTh[hf * 8 + 7][ql] = w21.w;
        __syncthreads();
#pragma unroll
        for (int q4 = 0; q4 < 32; ++q4) {
            float4 wv = *(const float4*)&WgTh[c][q4 * 4];
            float4 xv = *(const float4*)&XS[k][128 + q4 * 4];
            acc += wv.x * xv.x + wv.y * xv.y + wv.z * xv.z + wv.w * xv.w;
        }
        Pl[k][c] = acc;
    }
    __syncthreads();
    const int k = tid >> 4, m = tid & 15;
    {
        float d = 0.f;
#pragma unroll
        for (int c = 0; c < 16; ++c) d += Pl[k][c] * Pl[m][c];
        dotm[k][m] = d;
    }
    __syncthreads();
    {
        float v = dotm[k][k] + dotm[m][m] - 2.f * dotm[k][m];
        DsqS[k][m] = fmaxf(v, 0.f) * mk[k] * mk[m];
    }
    {
        float d = DsqS[k][m];
        float mm = mk[k] * mk[m];
#pragma unroll
        for (int s = 0; s < 3; ++s) {
            float i2 = 1.f / (2.f * expf(2.f * ls[s]) + 1e-8f);
            Wh[s][k][m] = (k == m) ? 0.f : expf(-d * i2) * mm;
        }
    }
    __syncthreads();
    if (tid < 48) {
        int s = tid >> 4, j = tid & 15;
        float t = 0.f;
        for (int i = 0; i < j; ++i) {
            float d = 0.f;
            for (int jj = j + 1; jj < 16; ++jj) d += Wh[s][j][jj] * Wh[s][i][jj];
            t += Wh[s][i][j] * d;
        }
        Ts[s * 16 + j] = t;
    }
    __syncthreads();
    float gd = 0.f;
#pragma unroll
    for (int o = 0; o < 16; ++o) {
        if (o == m) continue;
        int u = o < m ? o : m, v = o < m ? m : o;
        float gu = (u == k) ? (float)(2 * k - 15) : ((u > k) ? 1.f : -1.f);
        float gv = (v == k) ? (float)(2 * k - 15) : ((v > k) ? 1.f : -1.f);
        gd += -gu * mk[u] + gv * mk[v];
        if (u == k || v == k) gd += TAU;
    }
#pragma unroll
    for (int s = 0; s < 3; ++s) {
        float rs = 0.f;
#pragma unroll
        for (int o = 0; o < 16; ++o) rs += Wh[s][k][o];
        float l0 = (k == m) ? (rs + TAU) : -Wh[s][k][m];
        float G = gd + ((k == m) ? 4.f * Ts[s * 16 + k] : 0.f);
        Ms[s * 256 + tid] = l0;
        Ms[768 + s * 256 + tid] = G;
        float gg = G;
        for (int off = 8; off; off >>= 1) gg += __shfl_down(gg, off, 16);
        if (m == 0) gbuf[b * 48 + k * 3 + s] = 0.5f * gg;
    }
    __syncthreads();

    // Mcat rows: thread handles 2 adjacent q for 3 rt's (pair-packed stores)
    {
        const int q2 = (tid & 127) * 2;
        const int rtbase = (tid >> 7) * 3;
        float xv0[16], xv1[16];
#pragma unroll
        for (int l = 0; l < 16; ++l) { xv0[l] = XS[l][q2]; xv1[l] = XS[l][q2 + 1]; }
        const size_t obase = (size_t)b * 16 * 1536;
#pragma unroll
        for (int rtt = 0; rtt < 3; ++rtt) {
            const int rt = rtbase + rtt;
#pragma unroll
            for (int kk = 0; kk < 16; ++kk) {
                const float4* mp = (const float4*)&Ms[rt * 256 + kk * 16];
                float4 m0 = mp[0], m1 = mp[1], m2 = mp[2], m3 = mp[3];
                float a0 = m0.x * xv0[0] + m0.y * xv0[1] + m0.z * xv0[2] + m0.w * xv0[3]
                         + m1.x * xv0[4] + m1.y * xv0[5] + m1.z * xv0[6] + m1.w * xv0[7]
                         + m2.x * xv0[8] + m2.y * xv0[9] + m2.z * xv0[10] + m2.w * xv0[11]
                         + m3.x * xv0[12] + m3.y * xv0[13] + m3.z * xv0[14] + m3.w * xv0[15];
                float a1 = m0.x * xv1[0] + m0.y * xv1[1] + m0.z * xv1[2] + m0.w * xv1[3]
                         + m1.x * xv1[4] + m1.y * xv1[5] + m1.z * xv1[6] + m1.w * xv1[7]
                         + m2.x * xv1[8] + m2.y * xv1[9] + m2.z * xv1[10] + m2.w * xv1[11]
                         + m3.x * xv1[12] + m3.y * xv1[13] + m3.z * xv1[14] + m3.w * xv1[15];
                uint_t pk = (uint_t)f2bf(a0) | ((uint_t)f2bf(a1) << 16);
                *(uint_t*)&Mcat[obase + (size_t)kk * 1536 + rt * 256 + q2] = pk;
            }
        }
    }
}

// ---------------------------------------------------------------------------
// gemm64_dbs: 64x128 tile, BK=32, 2-phase double-buffer (round-3 proven),
// generalized with separate K row-stride and K loop length (split-K support:
// caller offsets A/Bt by the K-window base). Kstride==Klen reproduces the
// original core bit-for-bit.
// ---------------------------------------------------------------------------
__device__ __forceinline__ void gemm64_dbs(
    const ushort_t* __restrict__ A, const ushort_t* __restrict__ Bt,
    int Kstride, int Klen, int m0, int n0, f32x4 acc[2][4],
    ushort_t (*As0)[32], ushort_t (*As1)[32],
    ushort_t (*Bs0)[32], ushort_t (*Bs1)[32]) {
    const int tid = threadIdx.x;
    const int wave = tid >> 6, lane = tid & 63;
    const int lq = lane >> 4, lr = lane & 15;
    const int wm = wave >> 1, wn = wave & 1;
    const int r = tid >> 2, ca = (tid & 3) << 3;
    const ushort_t* Ag  = A  + (size_t)(m0 + r) * Kstride + ca;
    const ushort_t* Bg0 = Bt + (size_t)(n0 + r) * Kstride + ca;
    const ushort_t* Bg1 = Bt + (size_t)(n0 + 64 + r) * Kstride + ca;
    char* aD0  = (char*)As0 + wave * 1024;
    char* aD1  = (char*)As1 + wave * 1024;
    char* b0D0 = (char*)Bs0 + wave * 1024;
    char* b0D1 = (char*)Bs0 + 4096 + wave * 1024;
    char* b1D0 = (char*)Bs1 + wave * 1024;
    char* b1D1 = (char*)Bs1 + 4096 + wave * 1024;

    glds16(Ag, aD0); glds16(Bg0, b0D0); glds16(Bg1, b0D1);

    for (int kt = 0; kt < Klen; kt += 64) {
        {
            const int kn = kt + 32;
            if (kn < Klen) {
                glds16(Ag + kn, aD1); glds16(Bg0 + kn, b1D0); glds16(Bg1 + kn, b1D1);
                asm volatile("s_waitcnt vmcnt(3)" ::: "memory");
            } else {
                asm volatile("s_waitcnt vmcnt(0)" ::: "memory");
            }
            __builtin_amdgcn_s_barrier();
            short8 af[2], bfr[4];
#pragma unroll
            for (int i = 0; i < 2; ++i) af[i] = *(const short8*)&As0[wm * 32 + i * 16 + lr][lq * 8];
#pragma unroll
            for (int j = 0; j < 4; ++j) bfr[j] = *(const short8*)&Bs0[wn * 64 + j * 16 + lr][lq * 8];
#pragma unroll
            for (int i = 0; i < 2; ++i)
#pragma unroll
                for (int j = 0; j < 4; ++j)
                    acc[i][j] = __builtin_amdgcn_mfma_f32_16x16x32_bf16(af[i], bfr[j], acc[i][j], 0, 0, 0);
            asm volatile("s_waitcnt lgkmcnt(0)" ::: "memory");
            __builtin_amdgcn_s_barrier();
        }
        {
            const int kn = kt + 64;
            if (kn < Klen) {
                glds16(Ag + kn, aD0); glds16(Bg0 + kn, b0D0); glds16(Bg1 + kn, b0D1);
                asm volatile("s_waitcnt vmcnt(3)" ::: "memory");
            } else {
                asm volatile("s_waitcnt vmcnt(0)" ::: "memory");
            }
            __builtin_amdgcn_s_barrier();
            short8 af[2], bfr[4];
#pragma unroll
            for (int i = 0; i < 2; ++i) af[i] = *(const short8*)&As1[wm * 32 + i * 16 + lr][lq * 8];
#pragma unroll
            for (int j = 0; j < 4; ++j) bfr[j] = *(const short8*)&Bs1[wn * 64 + j * 16 + lr][lq * 8];
#pragma unroll
            for (int i = 0; i < 2; ++i)
#pragma unroll
                for (int j = 0; j < 4; ++j)
                    acc[i][j] = __builtin_amdgcn_mfma_f32_16x16x32_bf16(af[i], bfr[j], acc[i][j], 0, 0, 0);
            asm volatile("s_waitcnt lgkmcnt(0)" ::: "memory");
            __builtin_amdgcn_s_barrier();
        }
    }
}

// kZY split-K partial: M=16384, N=256, K=1536 split into 2 halves of 768.
// grid (256, 2, 2): z = K-half. Each block = proven 64x128 tile over its
// half -> 1024 blocks (4/CU, was 2/CU) at UNCHANGED tile shape & A traffic.
// Writes raw f32 partials; reduction + epilogue folds into k_ln2c.
__global__ __launch_bounds__(256) void kZY_part(
    const ushort_t* __restrict__ Mcat, const ushort_t* __restrict__ WcatT,
    float* __restrict__ P0, float* __restrict__ P1) {
    __shared__ ushort_t As0[64][32], As1[64][32];
    __shared__ ushort_t Bs0[128][32], Bs1[128][32];
    const int tid = threadIdx.x;
    const int m0 = blockIdx.x * 64, n0 = blockIdx.y * 128;
    const int koff = blockIdx.z * 768;
    f32x4 acc[2][4] = {};
    gemm64_dbs(Mcat + koff, WcatT + koff, 1536, 768, m0, n0, acc, As0, As1, Bs0, Bs1);
    float* P = blockIdx.z ? P1 : P0;
    const int wave = tid >> 6, lane = tid & 63, lq = lane >> 4, lr = lane & 15;
    const int wm = wave >> 1, wn = wave & 1;
#pragma unroll
    for (int i = 0; i < 2; ++i)
#pragma unroll
        for (int j = 0; j < 4; ++j) {
            int nl = wn * 64 + j * 16 + lr;
#pragma unroll
            for (int v = 0; v < 4; ++v) {
                int rl = wm * 32 + i * 16 + lq * 4 + v;
                P[(size_t)(m0 + rl) * 256 + n0 + nl] = acc[i][j][v];
            }
        }
}

// k_ln2c: xp = P0 + P1 + x + cv + sum_s g_s*beWo_s; write xp (f32) and
// h = LN2(xp) (bf16). grid 4096, 4 rows/block (one row per wave).
__global__ __launch_bounds__(256) void k_ln2c(
    const float* __restrict__ P0, const float* __restrict__ P1,
    const float* __restrict__ xin, const float* __restrict__ bo,
    const float* __restrict__ cvpart, const float* __restrict__ beWo,
    const float* __restrict__ gbuf, const float* __restrict__ g2,
    const float* __restrict__ b2, float* __restrict__ xp,
    ushort_t* __restrict__ h) {
    const int tid = threadIdx.x;
    const int row = blockIdx.x * 4 + (tid >> 6);
    const int lane = tid & 63;
    const float* gp = gbuf + (size_t)row * 3;
    const float ga = gp[0], gb = gp[1], gc = gp[2];
    const size_t base = (size_t)row * 256;
    float v[4];
#pragma unroll
    for (int c4 = 0; c4 < 4; ++c4) {
        const int col = lane + c4 * 64;
        float cv = bo[col] + TAU * (cvpart[col] + cvpart[256 + col] + cvpart[512 + col]);
        v[c4] = P0[base + col] + P1[base + col] + xin[base + col] + cv
              + ga * beWo[col] + gb * beWo[256 + col] + gc * beWo[512 + col];
        xp[base + col] = v[c4];
    }
    float s = v[0] + v[1] + v[2] + v[3];
    for (int m = 32; m; m >>= 1) s += __shfl_xor(s, m, 64);
    float mean = s * (1.f / 256.f);
    float d0 = v[0] - mean, d1 = v[1] - mean, d2 = v[2] - mean, d3 = v[3] - mean;
    float q = d0 * d0 + d1 * d1 + d2 * d2 + d3 * d3;
    for (int m = 32; m; m >>= 1) q += __shfl_xor(q, m, 64);
    float rstd = rsqrtf(q * (1.f / 256.f) + LN_EPS);
    ushort_t* hr = h + base;
    hr[lane] = f2bf(d0 * rstd * g2[lane] + b2[lane]);
    hr[lane + 64] = f2bf(d1 * rstd * g2[lane + 64] + b2[lane + 64]);
    hr[lane + 128] = f2bf(d2 * rstd * g2[lane + 128] + b2[lane + 128]);
    hr[lane + 192] = f2bf(d3 * rstd * g2[lane + 192] + b2[lane + 192]);
}

// K3: F1g = gelu(h @ Wf1 + bf1), 64x128 tiles, grid (256,8) = 2048 blocks
__global__ __launch_bounds__(256) void k3_gemm(const ushort_t* __restrict__ h,
                                               const ushort_t* __restrict__ Wf1T,
                                               const float* __restrict__ bf1,
                                               ushort_t* __restrict__ F1g) {
    __shared__ ushort_t As0[64][32], As1[64][32];
    __shared__ ushort_t Bs0[128][32], Bs1[128][32];
    const int tid = threadIdx.x;
    const int m0 = blockIdx.x * 64, n0 = blockIdx.y * 128;
    f32x4 acc[2][4] = {};
    gemm64_dbs(h, Wf1T, 256, 256, m0, n0, acc, As0, As1, Bs0, Bs1);
    const int wave = tid >> 6, lane = tid & 63, lq = lane >> 4, lr = lane & 15;
    const int wm = wave >> 1, wn = wave & 1;
#pragma unroll
    for (int i = 0; i < 2; ++i)
#pragma unroll
        for (int j = 0; j < 4; ++j) {
            int n = n0 + wn * 64 + j * 16 + lr;
            float bn = bf1[n];
#pragma unroll
            for (int v = 0; v < 4; ++v) {
                int rg = m0 + wm * 32 + i * 16 + lq * 4 + v;
                float u = acc[i][j][v] + bn;
                float gl = 0.5f * u * (1.f + erff(u * 0.70710678118f));
                F1g[(size_t)rg * 1024 + n] = f2bf(gl);
            }
        }
}

// K4: out = xp + F1g @ Wf2 + bf2, 64x128 tiles, grid (256,2)
__global__ __launch_bounds__(256) void k4_gemm(const ushort_t* __restrict__ F1g,
                                               const ushort_t* __restrict__ Wf2T,
                                               const float* __restrict__ bf2,
                                               const float* __restrict__ xp,
                                               float* __restrict__ out) {
    __shared__ ushort_t As0[64][32], As1[64][32];
    __shared__ ushort_t Bs0[128][32], Bs1[128][32];
    const int tid = threadIdx.x;
    const int m0 = blockIdx.x * 64, n0 = blockIdx.y * 128;
    f32x4 acc[2][4] = {};
    gemm64_dbs(F1g, Wf2T, 1024, 1024, m0, n0, acc, As0, As1, Bs0, Bs1);
    const int wave = tid >> 6, lane = tid & 63, lq = lane >> 4, lr = lane & 15;
    const int wm = wave >> 1, wn = wave & 1;
#pragma unroll
    for (int i = 0; i < 2; ++i)
#pragma unroll
        for (int j = 0; j < 4; ++j) {
            int n = n0 + wn * 64 + j * 16 + lr;
            float bn = bf2[n];
#pragma unroll
            for (int v = 0; v < 4; ++v) {
                size_t idx = (size_t)(m0 + wm * 32 + i * 16 + lq * 4 + v) * 256 + n;
                out[idx] = xp[idx] + acc[i][j][v] + bn;
            }
        }
}

extern "C" void kernel_launch(void* const* d_in, const int* in_sizes, int n_in,
                              void* d_out, int out_size, void* d_ws, size_t ws_size,
                              hipStream_t stream) {
    const float* x = (const float*)d_in[0];
    const float* mask = (const float*)d_in[1];
    const float* Wg = (const float*)d_in[2];
    const float* bg = (const float*)d_in[3];
    const float* ls = (const float*)d_in[4];
    const float* Wv = (const float*)d_in[5];
    const float* bv = (const float*)d_in[6];
    const float* We = (const float*)d_in[7];
    const float* be = (const float*)d_in[8];
    const float* Wo = (const float*)d_in[9];
    const float* bo = (const float*)d_in[10];
    const float* g1 = (const float*)d_in[11];
    const float* b1 = (const float*)d_in[12];
    const float* g2 = (const float*)d_in[13];
    const float* b2 = (const float*)d_in[14];
    const float* Wf1 = (const float*)d_in[15];
    const float* bf1 = (const float*)d_in[16];
    const float* Wf2 = (const float*)d_in[17];
    const float* bf2 = (const float*)d_in[18];
    float* out = (float*)d_out;

    char* ws = (char*)d_ws;
    ushort_t* Mcat = (ushort_t*)(ws);                   // 50,331,648 (kA->kZY)
    ushort_t* F1g = (ushort_t*)(ws);                    // 33,554,432 (k3->k4; Mcat dead)
    ushort_t* WcatT = (ushort_t*)(ws + 50331648);       //    786,432
    ushort_t* Wf1T = (ushort_t*)(ws + 51118080);        //    524,288
    ushort_t* Wf2T = (ushort_t*)(ws + 51642368);        //    524,288
    float* cvpart = (float*)(ws + 52166656);            //      3,072
    float* beWo = (float*)(ws + 52169728);              //      3,072
    float* gbuf = (float*)(ws + 52172800);              //    196,608
    float* xp = (float*)(ws + 52369408);                // 16,777,216
    ushort_t* h = (ushort_t*)(ws + 69146624);           //  8,388,608
    float* P0 = (float*)(ws + 77535232);                // 16,777,216
    float* P1 = (float*)(ws + 94312448);                // 16,777,216 -> end 111,089,664

    kA<<<dim3(1542), dim3(256), 0, stream>>>(x, mask, Wg, bg, ls, g1, b1,
                                             Mcat, gbuf,
                                             Wv, We, Wo, bv, be, Wf1, Wf2,
                                             WcatT, Wf1T, Wf2T, cvpart, beWo);
    kZY_part<<<dim3(256, 2, 2), dim3(256), 0, stream>>>(Mcat, WcatT, P0, P1);
    k_ln2c<<<dim3(4096), dim3(256), 0, stream>>>(P0, P1, x, bo, cvpart, beWo,
                                                 gbuf, g2, b2, xp, h);
    k3_gemm<<<dim3(256, 8), dim3(256), 0, stream>>>(h, Wf1T, bf1, F1g);
    k4_gemm<<<dim3(256, 2), dim3(256), 0, stream>>>(F1g, Wf2T, bf2, xp, out);
}